// Round 12
// baseline (405.104 us; speedup 1.0000x reference)
//
#include <hip/hip_runtime.h>
#include <hip/hip_bf16.h>
#include <math.h>

#define E_EDGES 50000
#define NN 5000

typedef __hip_bfloat16 bf16;
typedef __attribute__((ext_vector_type(8))) short short8;
typedef __attribute__((ext_vector_type(4))) float f32x4;
typedef __attribute__((ext_vector_type(2))) _Float16 h2;

__device__ __forceinline__ float b2f(bf16 v) { return __bfloat162float(v); }
__device__ __forceinline__ float siluf(float x) { return x / (1.0f + __expf(-x)); }
__device__ __forceinline__ float us2f(unsigned short u) {
  union { unsigned int i; float f; } c; c.i = ((unsigned int)u) << 16; return c.f;
}

__device__ __forceinline__ float fdot2f(h2 a, h2 b, float c) {
#if __has_builtin(__builtin_amdgcn_fdot2)
  return __builtin_amdgcn_fdot2(a, b, c, false);
#else
  return c + (float)a.x*(float)b.x + (float)a.y*(float)b.y;
#endif
}
__device__ __forceinline__ float dot8h(uint4 w, uint4 t, float acc) {
  acc = fdot2f(__builtin_bit_cast(h2, w.x), __builtin_bit_cast(h2, t.x), acc);
  acc = fdot2f(__builtin_bit_cast(h2, w.y), __builtin_bit_cast(h2, t.y), acc);
  acc = fdot2f(__builtin_bit_cast(h2, w.z), __builtin_bit_cast(h2, t.z), acc);
  acc = fdot2f(__builtin_bit_cast(h2, w.w), __builtin_bit_cast(h2, t.w), acc);
  return acc;
}

// ================= merged setup: prep(+hists) | fuse->Mbb | embed | w0rtb | w2t =================
__global__ void __launch_bounds__(256) k_setup(
    const float* __restrict__ evec, const float* __restrict__ elen,
    float* __restrict__ shb, float* __restrict__ bc,
    const float* __restrict__ w2, const float* __restrict__ b2,
    const float* __restrict__ w01, const float* __restrict__ w11,
    bf16* __restrict__ Mbb,
    float* __restrict__ bias0, float* __restrict__ bias1,
    const float* __restrict__ emb, const int* __restrict__ an,
    float* __restrict__ node0, bf16* __restrict__ node0b,
    const float* __restrict__ w0, bf16* __restrict__ W0rtb,
    const float* __restrict__ w1w2, bf16* __restrict__ W2t,
    const int* __restrict__ ei, int* __restrict__ hist, int* __restrict__ hist2) {
  const int b = blockIdx.x, tid = threadIdx.x;
  if (b < 196) {                      // ---- prep (sh + basis*cutoff) + src/dst histograms
    int e = b*256 + tid;
    if (e >= E_EDGES) return;
    atomicAdd(&hist[ei[e]], 1);
    atomicAdd(&hist2[ei[E_EDGES + e]], 1);
    float x = evec[3*e+0], y = evec[3*e+1], z = evec[3*e+2];
    float r = elen[e];
    float inv = 1.0f / (r + 1e-8f);
    float ux = x*inv, uy = y*inv, uz = z*inv;
    const float s3 = 1.7320508075688772f, s5 = 2.2360679774997896f, s15 = 3.8729833462074170f;
    float* sh = shb + (size_t)e*12;
    sh[0] = 1.0f;
    sh[1] = s3*uy; sh[2] = s3*uz; sh[3] = s3*ux;
    sh[4] = s15*ux*uy; sh[5] = s15*uy*uz; sh[6] = 0.5f*s5*(3.0f*uz*uz - 1.0f);
    sh[7] = s15*ux*uz; sh[8] = 0.5f*s15*(ux*ux - uy*uy);
    sh[9] = 0.f; sh[10] = 0.f; sh[11] = 0.f;
    float rr = fmaxf(r, 1e-8f);
    const float pi = 3.14159265358979f;
    float xr = r * 0.2f;
    float cut = (xr < 1.0f) ? 0.5f*(1.0f + cosf(pi*xr)) : 0.0f;
    float fb = pi * 0.2f;
    for (int k = 1; k <= 8; ++k)
      bc[(size_t)e*8 + (k-1)] = sinf(fb*(float)k*r)/rr * cut;
  } else if (b < 212) {               // ---- fuse rad_w2 into wnn*_w1 -> Mbb (B-layout bf16)
    int i = (b-196)*256 + tid;        // 4096
    int hh = i >> 6, c = i & 63;
    float a0 = 0.f, a1 = 0.f;
    for (int j = 0; j < 64; ++j) {
      float wv = w2[hh*64 + j];
      a0 += wv * w01[j*64 + c];
      a1 += wv * w11[j*64 + c];
    }
    Mbb[(size_t)c*64 + hh]        = __float2bfloat16(a0);
    Mbb[(size_t)(64 + c)*64 + hh] = __float2bfloat16(a1);
    if (hh == 0) {
      float s0 = 0.f, s1 = 0.f;
      for (int j = 0; j < 64; ++j) {
        s0 += b2[j] * w01[j*64 + c];
        s1 += b2[j] * w11[j*64 + c];
      }
      bias0[c] = s0;
      bias1[c] = s1;
    }
  } else if (b < 1462) {              // ---- embed (320000 exact): fp32 + bf16 copies
    int i = (b-212)*256 + tid;
    int n = i >> 6, c = i & 63;
    float v = emb[an[n]*64 + c];
    node0[i] = v;
    node0b[i] = __float2bfloat16(v);
  } else if (b < 2358) {              // ---- W0rtb[col*64+u] bf16, col = h*56+vp (229376 exact)
    int idx = (b-1462)*256 + tid;
    int col = idx >> 6, u = idx & 63;
    int hh = col / 56, vp = col - hh*56;
    int boff, m3, v;
    if (vp < 32)      { boff = 0;    m3 = 32; v = vp; }
    else if (vp < 48) { boff = 2048; m3 = 16; v = vp - 32; }
    else              { boff = 3072; m3 = 8;  v = vp - 48; }
    W0rtb[idx] = __float2bfloat16(w0[hh*3584 + boff + u*m3 + v]);
  } else {                            // ---- w2t transpose + per-path [v][u] permute
    int idx = (b-2358)*256 + tid;     // 221184 exact
    int nn = idx >> 6, k = idx & 63;
    int p, loc;
    if (nn < 1024)      { p=0;  loc=nn;      }
    else if (nn < 1536) { p=1;  loc=nn-1024; }
    else if (nn < 1792) { p=2;  loc=nn-1536; }
    else if (nn < 2048) { p=3;  loc=nn-1792; }
    else if (nn < 2560) { p=4;  loc=nn-2048; }
    else if (nn < 2688) { p=5;  loc=nn-2560; }
    else if (nn < 2944) { p=6;  loc=nn-2688; }
    else if (nn < 3008) { p=7;  loc=nn-2944; }
    else if (nn < 3136) { p=8;  loc=nn-3008; }
    else if (nn < 3392) { p=9;  loc=nn-3136; }
    else                { p=10; loc=nn-3392; }
    const int M1s[11] = {32,32,32,16,16,16,16,8,8,8,8};
    const int M3s[11] = {32,16,8,16,32,8,16,8,16,32,8};
    int m1 = M1s[p], m3 = M3s[p];
    int v = loc / m1, u = loc - v*m1;
    int src = (nn - loc) + u*m3 + v;
    W2t[idx] = __float2bfloat16(w1w2[(size_t)k*3456 + src]);
  }
}

// ================= k_mid: rad (h-VALU + MFMA q-GEMM) | scan x2 =================
__global__ void __launch_bounds__(256) k_mid(
    const float* __restrict__ bc,
    const float* __restrict__ w1, const float* __restrict__ b1,
    const bf16* __restrict__ Mbb,
    const float* __restrict__ bias0, const float* __restrict__ bias1,
    float* __restrict__ q0, bf16* __restrict__ q1b,
    const int* __restrict__ hist, int* __restrict__ start,
    const int* __restrict__ hist2, int* __restrict__ start2) {
  __shared__ float smem[1024];
  __shared__ __align__(16) short sHb[2048];
  const int tid = threadIdx.x;
  const int b = blockIdx.x;
  if (b < 1563) {
    float* sW1 = smem;
    float* sB  = smem + 512;
    float* sb0 = smem + 576;
    float* sb1 = smem + 640;
    float* sBC = smem + 704;
    const int j = tid >> 6, m = tid & 63;
    for (int i = tid; i < 512; i += 256) sW1[i] = w1[i];
    if (tid < 64) { sB[tid] = b1[tid]; sb0[tid] = bias0[tid]; sb1[tid] = bias1[tid]; }
    {
      int e = b*32 + (tid >> 3);
      int k = tid & 7;
      int eL = e < E_EDGES ? e : E_EDGES-1;
      sBC[tid] = bc[(size_t)eL*8 + k];
    }
    __syncthreads();
    #pragma unroll
    for (int g = 0; g < 8; ++g) {
      int el = g*4 + j;
      float t = sB[m];
      #pragma unroll
      for (int k = 0; k < 8; ++k) t += sBC[el*8+k]*sW1[k*64+m];
      bf16 hv = __float2bfloat16(siluf(t));
      sHb[el*64 + m] = *(short*)&hv;
    }
    __syncthreads();
    const int w = tid >> 6, lane = tid & 63;
    const int row16 = lane & 15, quad = lane >> 4;
    const int mtile = w & 1, cg = w >> 1;
    const short* ap = sHb + (mtile*16 + row16)*64 + quad*8;
    short8 a0 = *(const short8*)ap;
    short8 a1 = *(const short8*)(ap + 32);
    f32x4 acc[4] = {};
    #pragma unroll
    for (int ni = 0; ni < 4; ++ni) {
      const short* bp = (const short*)Mbb + (size_t)(cg*64 + ni*16 + row16)*64 + quad*8;
      short8 b0 = *(const short8*)bp;
      short8 b1v = *(const short8*)(bp + 32);
      acc[ni] = __builtin_amdgcn_mfma_f32_16x16x32_bf16(a0, b0, acc[ni], 0,0,0);
      acc[ni] = __builtin_amdgcn_mfma_f32_16x16x32_bf16(a1, b1v, acc[ni], 0,0,0);
    }
    const float* bias = cg ? sb1 : sb0;
    #pragma unroll
    for (int ni = 0; ni < 4; ++ni) {
      int c = ni*16 + row16;
      float bv = bias[c];
      #pragma unroll
      for (int r = 0; r < 4; ++r) {
        int e = b*32 + mtile*16 + quad*4 + r;
        if (e < E_EDGES) {
          float val = siluf(acc[ni][r] + bv);
          if (cg == 0) q0[(size_t)e*64 + c] = val;
          else         q1b[(size_t)e*64 + c] = __float2bfloat16(val);
        }
      }
    }
  } else {
    const int* h = (b == 1563) ? hist : hist2;
    int* st      = (b == 1563) ? start : start2;
    int* sp = (int*)smem;
    int base = tid*20;
    int localsum = 0;
    for (int i = 0; i < 20; ++i) { int jj = base+i; localsum += (jj < NN) ? h[jj] : 0; }
    sp[tid] = localsum;
    __syncthreads();
    if (tid == 0) {
      int acc = 0;
      for (int i = 0; i < 256; ++i) { int t = sp[i]; sp[i] = acc; acc += t; }
    }
    __syncthreads();
    int run = sp[tid];
    for (int i = 0; i < 20; ++i) {
      int jj = base+i;
      if (jj < NN) { st[jj] = run; run += h[jj]; }
    }
    if (tid == 255) st[NN] = run;
  }
}

// ================= k_pre0: scat (src+dst CSR) | G0 MFMA GEMM (flattened) =================
__global__ void __launch_bounds__(256) k_pre0(
    const int* __restrict__ ei,
    const int* __restrict__ start, int* __restrict__ cursor, int* __restrict__ perm,
    const int* __restrict__ start2, int* __restrict__ cursor2, int* __restrict__ perm2,
    const bf16* __restrict__ A, const bf16* __restrict__ B, bf16* __restrict__ out) {
  __shared__ short lds[4][32*64];
  const int b = blockIdx.x, tid = threadIdx.x;
  if (b < 196) {
    int e = b*256 + tid;
    if (e >= E_EDGES) return;
    int src = ei[e];
    perm[start[src] + atomicAdd(&cursor[src], 1)] = e;
    int dst = ei[E_EDGES + e];
    perm2[start2[dst] + atomicAdd(&cursor2[dst], 1)] = e;
  } else {
    const int bb = b - 196;           // 14 x 157 blocks
    const int wid = tid >> 6, lane = tid & 63;
    const int nt = (bb % 14)*4 + wid;
    const int r0 = (bb / 14)*32;
    const int row16 = lane & 15, quad = lane >> 4;
    short8 a[2][2];
    #pragma unroll
    for (int mi = 0; mi < 2; ++mi) {
      int r = r0 + mi*16 + row16;
      int rg = (r < NN) ? r : 0;
      const short* ap = (const short*)A + (size_t)rg*64 + quad*8;
      a[mi][0] = *(const short8*)(ap);
      a[mi][1] = *(const short8*)(ap + 32);
    }
    if (nt < 56) {
      f32x4 acc[4][2] = {};
      #pragma unroll
      for (int ni = 0; ni < 4; ++ni) {
        int col = nt*64 + ni*16 + row16;
        const short* bp = (const short*)B + (size_t)col*64 + quad*8;
        short8 b0 = *(const short8*)(bp);
        short8 b1 = *(const short8*)(bp + 32);
        #pragma unroll
        for (int mi = 0; mi < 2; ++mi) {
          acc[ni][mi] = __builtin_amdgcn_mfma_f32_16x16x32_bf16(a[mi][0], b0, acc[ni][mi], 0,0,0);
          acc[ni][mi] = __builtin_amdgcn_mfma_f32_16x16x32_bf16(a[mi][1], b1, acc[ni][mi], 0,0,0);
        }
      }
      #pragma unroll
      for (int ni = 0; ni < 4; ++ni)
        #pragma unroll
        for (int mi = 0; mi < 2; ++mi)
          #pragma unroll
          for (int rr = 0; rr < 4; ++rr) {
            bf16 hv = __float2bfloat16(acc[ni][mi][rr]);
            lds[wid][(mi*16 + quad*4 + rr)*64 + ni*16 + row16] = *(short*)&hv;
          }
    }
    __syncthreads();
    if (nt < 56) {
      #pragma unroll
      for (int it = 0; it < 4; ++it) {
        int unit = it*64 + lane;
        int rrow = unit >> 3;
        int cu = (unit & 7) * 8;
        int r = r0 + rrow;
        if (r < NN)
          *(uint4*)((short*)out + (size_t)r*3584 + nt*64 + cu) =
              *(const uint4*)&lds[wid][rrow*64 + cu];
      }
    }
  }
}

// ================= layer-0 z: per-src-node; G0 row in LDS; z -> zbuf (no atomics) =================
__global__ void __launch_bounds__(256) k_msg0z(
    const float* __restrict__ q0, const bf16* __restrict__ G0,
    const int* __restrict__ start, const int* __restrict__ perm,
    float* __restrict__ zbuf) {
  __shared__ uint4 g4[448];
  __shared__ float sq[4][64];
  const int n = blockIdx.x;
  const int tid = threadIdx.x;
  const int wv = tid >> 6, lane = tid & 63;
  const uint4* gr = (const uint4*)(G0 + (size_t)n*3584);
  for (int i = tid; i < 448; i += 256) g4[i] = gr[i];
  const int s0 = start[n], s1 = start[n+1];
  __syncthreads();
  const short* gs = (const short*)g4;
  for (int base = s0; base < s1; base += 4) {
    int idx = base + wv;
    if (idx < s1) {
      int e = perm[idx];
      sq[wv][lane] = q0[(size_t)e*64 + lane];
      float z = 0.f;
      if (lane < 56) {
        #pragma unroll
        for (int h = 0; h < 64; ++h)
          z += sq[wv][h]*us2f((unsigned short)gs[h*56 + lane]);
        zbuf[(size_t)e*56 + lane] = z;
      }
    }
  }
}

// ================= layer-0 aggregate (dst-CSR) + self-connection -> node1 (2 nodes/block) =========
__global__ void __launch_bounds__(256) k_agg0(
    const float* __restrict__ zbuf, const float* __restrict__ shb,
    const int* __restrict__ start2, const int* __restrict__ perm2,
    const float* __restrict__ node0, const float* __restrict__ sc00,
    float* __restrict__ node1) {
  __shared__ float n0[2][64];
  int sub = threadIdx.x >> 7, t = threadIdx.x & 127;
  int n = blockIdx.x*2 + sub;                 // NN=5000 even: always < NN
  if (t < 64) n0[sub][t] = node0[(size_t)n*64 + t];
  __syncthreads();
  if (t >= 120) return;
  int c = t, zi, shi;
  if (c < 32)      { zi = c; shi = -1; }
  else if (c < 80) { int j = c-32, v = j/3, k = j - v*3; zi = 32 + v; shi = 1 + k; }
  else             { int j = c-80, v = j/5, k = j - v*5; zi = 48 + v; shi = 4 + k; }
  float acc = 0.f;
  const int s0 = start2[n], s1 = start2[n+1];
  for (int idx = s0; idx < s1; ++idx) {
    int e = perm2[idx];
    float z = zbuf[(size_t)e*56 + zi];
    acc += (shi < 0) ? z : z*shb[(size_t)e*12 + shi];
  }
  acc *= 0.125f * 0.3162277660168379f;
  if (c < 32) {
    float s = 0.f;
    for (int u = 0; u < 64; ++u) s += n0[sub][u]*sc00[u*32 + c];
    acc += s * 0.125f;
    acc = siluf(acc);
  }
  node1[(size_t)n*120 + c] = acc;
}

// ================= fused layer-1: per-edge weight GEMM (MFMA) + TP contraction =================
// v12 = v8 (best: 210us k_fuse): branchless w-loads, single MFMA_STORE in loop,
// f16 w/t, fdot2, launch_bounds(256,4). No t-prefetch (v11 neutral).

// tile tables (54 tiles of 64 cols over the 11 paths)
static __device__ const int TM1[54] = {
  32,32,32,32,32,32,32,32,32,32,32,32,32,32,32,32,
  32,32,32,32,32,32,32,32,
  32,32,32,32,
  16,16,16,16,
  16,16,16,16,16,16,16,16,
  16,16,
  16,16,16,16,
  8,
  8,8,
  8,8,8,8,
  8};
static __device__ const int TNK[54] = {
  1,1,1,1,1,1,1,1,1,1,1,1,1,1,1,1,
  3,3,3,3,3,3,3,3,
  5,5,5,5,
  3,3,3,3,
  1,1,1,1,1,1,1,1,
  5,5,
  3,3,3,3,
  5,
  3,3,
  1,1,1,1,
  5};
static __device__ const int TTOF[54] = {
  0,0,0,0,0,0,0,0,0,0,0,0,0,0,0,0,
  32,32,32,32,32,32,32,32,
  128,128,128,128,
  288,288,288,288,
  336,336,336,336,336,336,336,336,
  352,352,
  432,432,432,432,
  480,
  520,520,
  544,544,544,544,
  552};
static __device__ const int TOUT[54] = {
  0,2,4,6,8,10,12,14,16,18,20,22,24,26,28,30,
  32,38,44,50,56,62,68,74,
  80,90,100,110,
  32,44,56,68,
  0,4,8,12,16,20,24,28,
  80,100,
  32,44,56,68,
  80,
  32,56,
  0,8,16,24,
  80};

#define STB(ST, VAL) { _Float16 hv_ = (_Float16)(VAL); tp[ST] = *(short*)&hv_; }

// store full 64-col f16 w-tile, 16B-block swizzled by e&7
#define STORE_WL(ACC) { \
    _Pragma("unroll") \
    for (int ni_ = 0; ni_ < 4; ++ni_) { \
      _Pragma("unroll") \
      for (int r_ = 0; r_ < 4; ++r_) { \
        int e_ = quad*4 + r_; \
        int c_ = ni_*16 + row16; \
        _Float16 hv_ = (_Float16)((ACC)[ni_][r_]); \
        wl16[e_*64 + ((((c_>>3) ^ (e_&7))<<3) | (c_&7))] = *(short*)&hv_; \
      } \
    } }

// MFMA tile (NTT), prefetch frags for NTT+4, store f16 tile
#define MFMA_STORE(NTT) { \
    f32x4 acc_[4] = {}; \
    _Pragma("unroll") \
    for (int ni_ = 0; ni_ < 4; ++ni_) { \
      acc_[ni_] = __builtin_amdgcn_mfma_f32_16x16x32_bf16(a0, bf0[ni_], acc_[ni_], 0,0,0); \
      acc_[ni_] = __builtin_amdgcn_mfma_f32_16x16x32_bf16(a1, bf1[ni_], acc_[ni_], 0,0,0); \
    } \
    if ((NTT) + 4 < 54) { \
      _Pragma("unroll") \
      for (int ni_ = 0; ni_ < 4; ++ni_) { \
        const short* bp_ = (const short*)W2t + (size_t)(((NTT)+4)*64 + ni_*16 + row16)*64 + quad*8; \
        bf0[ni_] = *(const short8*)bp_; \
        bf1[ni_] = *(const short8*)(bp_ + 32); \
      } \
    } \
    STORE_WL(acc_) }

// compute bodies (t loads + dots + atomics fully inside each branch)
#define COMP32(NKC) { \
    const short* tb = tls16 + e*600 + toff + ((g >> 1) << 4); \
    _Pragma("unroll") \
    for (int k_ = 0; k_ < NKC; ++k_) { \
      uint4 t0 = *(const uint4*)&tb[k_*32]; \
      uint4 t1 = *(const uint4*)&tb[k_*32 + 8]; \
      float ak = dot8h(wr0, t0, 0.f); \
      ak = dot8h(wr1, t1, ak); \
      ak += __shfl_xor(ak, 32); \
      if (g < 2) atomicAdd(&msgl[e*121 + tout + (g&1)*(NKC) + k_], ak); \
    } }
#define COMP16(NKC) { \
    const short* tb = tls16 + e*600 + toff; \
    _Pragma("unroll") \
    for (int k_ = 0; k_ < NKC; ++k_) { \
      uint4 t0 = *(const uint4*)&tb[k_*16]; \
      uint4 t1 = *(const uint4*)&tb[k_*16 + 8]; \
      float ak = dot8h(wr0, t0, 0.f); \
      ak = dot8h(wr1, t1, ak); \
      atomicAdd(&msgl[e*121 + tout + g*(NKC) + k_], ak); \
    } }
#define COMP8(NKC) { \
    const short* tb = tls16 + e*600 + toff; \
    _Pragma("unroll") \
    for (int k_ = 0; k_ < NKC; ++k_) { \
      uint4 t0 = *(const uint4*)&tb[k_*8]; \
      float ak = dot8h(wr0, t0, 0.f); \
      atomicAdd(&msgl[e*121 + tout + g*(NKC) + k_], ak); \
      float ak2 = dot8h(wr1, t0, 0.f); \
      atomicAdd(&msgl[e*121 + tout + (g+4)*(NKC) + k_], ak2); \
    } }

__global__ void __launch_bounds__(256, 4) k_fuse(
    const bf16* __restrict__ q1b, const bf16* __restrict__ W2t,
    const float* __restrict__ node1, const float* __restrict__ shb,
    const int* __restrict__ ei, float* __restrict__ msg1) {
  __shared__ __align__(16) short tls16[16*600];  // 19,200 B: t f16, [k][u] per path
  __shared__ __align__(16) short wls16[4*1024];  // 8,192 B: phase A x[16][120] fp32 / phase B f16 w-tiles
  __shared__ float msgl[16*121];                 // 7,744 B (odd word stride)
  __shared__ float shl[16*12];                   // 768 B
  float* xl = (float*)wls16;

  const int tid = threadIdx.x;
  const int wv = tid >> 6, lane = tid & 63;
  const int e0 = blockIdx.x * 16;               // 3125 * 16 == 50000 exact
  const int row16 = lane & 15, quad = lane >> 4;

  // ---- cooperative load: x (node1[src]) + sh; zero msg ----
  {
    int e = tid >> 4, c0 = tid & 15;
    int src = ei[e0 + e];
    const float* xp = node1 + (size_t)src*120;
    for (int c = c0; c < 120; c += 16) xl[e*120 + c] = xp[c];
    if (c0 < 12) shl[e*12 + c0] = shb[(size_t)(e0+e)*12 + c0];
  }
  for (int i = tid; i < 1936; i += 256) msgl[i] = 0.f;

  // ---- A-fragments + first-tile B-fragments (issued before phase A to hide latency) ----
  const short* ap = (const short*)q1b + (size_t)(e0 + row16)*64 + quad*8;
  short8 a0 = *(const short8*)ap;
  short8 a1 = *(const short8*)(ap + 32);
  short8 bf0[4], bf1[4];
  #pragma unroll
  for (int ni = 0; ni < 4; ++ni) {
    const short* bp = (const short*)W2t + (size_t)(wv*64 + ni*16 + row16)*64 + quad*8;
    bf0[ni] = *(const short8*)bp;
    bf1[ni] = *(const short8*)(bp + 32);
  }

  __syncthreads();

  // ================= phase A: type-per-wave, all 64 lanes uniform per pass =================
  {
    const float Av = 0.3162277660168379f, Bc = 0.1825741858350554f, B2 = 0.3651483716701107f;
    const int I_[11] = {0,2,0,1,1,2, 0,1,2, 0,2};
    const int J_[11] = {2,0,1,0,2,1, 0,1,2, 0,2};
    const int K_[11] = {0,0,1,1,3,3, 2,2,2, 4,4};
    const float V_[11] = {Av,Av,Av,Av,Av,Av, -Bc,B2,-Bc, -Av,Av};
    const float P = 0.2390457218668787f, Q = 0.2070196678027063f, R = 0.1195228609334394f;
    const int I2_[25] = {0,0,2, 0,0,1,1,3,3, 1,1,2, 1,1,4, 2, 2,3,3, 2,4,4, 3,3,4};
    const int J2_[25] = {0,2,0, 1,3,0,3,0,1, 1,2,1, 1,4,1, 2, 3,2,3, 4,2,4, 3,4,3};
    const int K2_[25] = {2,0,0, 3,1,3,0,1,0, 2,1,1, 4,1,1, 2, 3,3,2, 4,4,2, 4,3,3};
    const float V2_[25] = {P,P,P, -Q,-Q,-Q,-Q,-Q,-Q, -R,-R,-R, Q,Q,Q, -P,
                           -R,-R,-R, P,P,P, -Q,-Q,-Q};

    if (wv == 0) {
      #pragma unroll
      for (int p = 0; p < 12; ++p) {          // T3
        int j = p*64 + lane;
        int e = j/48, r = j - e*48;
        int u = r/3, k = r - u*3;
        const float* x = xl + e*120;
        short* tp = tls16 + e*600;
        STB(288 + k*16 + u, x[32+u*3+k]*0.1178511301977579f);
      }
      #pragma unroll
      for (int p = 0; p < 4; ++p) {           // T4
        int j = p*64 + lane;
        int e = j >> 4, u = j & 15;
        const float* x = xl + e*120; const float* sh = shl + e*12;
        short* tp = tls16 + e*600;
        STB(336 + u, (x[32+u*3]*sh[1] + x[32+u*3+1]*sh[2] + x[32+u*3+2]*sh[3])
                     * 0.0771516749810460f);
      }
      #pragma unroll
      for (int p = 0; p < 2; ++p) {           // T10
        int j = p*64 + lane;
        int e = j >> 3, u = j & 7;
        const float* x = xl + e*120; const float* sh = shl + e*12;
        short* tp = tls16 + e*600;
        float y0 = x[80+u*5], y1 = x[80+u*5+1], y2 = x[80+u*5+2],
              y3 = x[80+u*5+3], y4 = x[80+u*5+4];
        float o0=0.f,o1=0.f,o2=0.f,o3=0.f,o4=0.f;
        #pragma unroll
        for (int q = 0; q < 25; ++q) {
          float xv = (I2_[q]==0) ? y0 : ((I2_[q]==1) ? y1 : ((I2_[q]==2) ? y2 :
                     ((I2_[q]==3) ? y3 : y4)));
          float term = V2_[q]*xv*sh[4+J2_[q]];
          if (K2_[q]==0) o0 += term; else if (K2_[q]==1) o1 += term;
          else if (K2_[q]==2) o2 += term; else if (K2_[q]==3) o3 += term; else o4 += term;
        }
        const float sc = 0.2795084971874737f;
        STB(552 + u, o0*sc); STB(552 + 8 + u, o1*sc); STB(552 + 16 + u, o2*sc);
        STB(552 + 24 + u, o3*sc); STB(552 + 32 + u, o4*sc);
      }
    } else if (wv == 1) {
      #pragma unroll
      for (int p = 0; p < 10; ++p) {          // T7
        int j = p*64 + lane;
        int e = j/40, r = j - e*40;
        int u = r/5, k = r - u*5;
        const float* x = xl + e*120;
        short* tp = tls16 + e*600;
        STB(480 + k*8 + u, x[80+u*5+k]*0.125f);
      }
      #pragma unroll
      for (int p = 0; p < 4; ++p) {           // T5
        int j = p*64 + lane;
        int e = j >> 4, u = j & 15;
        const float* x = xl + e*120; const float* sh = shl + e*12;
        short* tp = tls16 + e*600;
        float x0 = x[32+u*3], x1 = x[32+u*3+1], x2 = x[32+u*3+2];
        float o0=0.f,o1=0.f,o2=0.f,o3=0.f,o4=0.f;
        #pragma unroll
        for (int q = 0; q < 11; ++q) {
          float xv = (I_[q]==0) ? x0 : ((I_[q]==1) ? x1 : x2);
          float term = V_[q]*xv*sh[1+J_[q]];
          if (K_[q]==0) o0 += term; else if (K_[q]==1) o1 += term;
          else if (K_[q]==2) o2 += term; else if (K_[q]==3) o3 += term; else o4 += term;
        }
        const float sc = 0.2795084971874737f;
        STB(352 + u, o0*sc); STB(352 + 16 + u, o1*sc); STB(352 + 32 + u, o2*sc);
        STB(352 + 48 + u, o3*sc); STB(352 + 64 + u, o4*sc);
      }
      #pragma unroll
      for (int p = 0; p < 2; ++p) {           // T9
        int j = p*64 + lane;
        int e = j >> 3, u = j & 7;
        const float* x = xl + e*120; const float* sh = shl + e*12;
        short* tp = tls16 + e*600;
        STB(544 + u, (x[80+u*5]*sh[4] + x[80+u*5+1]*sh[5] + x[80+u*5+2]*sh[6]
                    + x[80+u*5+3]*sh[7] + x[80+u*5+4]*sh[8]) * 0.0597614304667197f);
      }
    } else if (wv == 2) {
      #pragma unroll
      for (int p = 0; p < 8; ++p) {           // T0
        int j = p*64 + lane;
        int e = j >> 5, u = j & 31;
        const float* x = xl + e*120;
        short* tp = tls16 + e*600;
        STB(u, x[u] * 0.1336306209562122f);
      }
      #pragma unroll
      for (int p = 0; p < 4; ++p) {           // T6
        int j = p*64 + lane;
        int e = j >> 4, u = j & 15;
        const float* x = xl + e*120; const float* sh = shl + e*12;
        short* tp = tls16 + e*600;
        float x0 = x[32+u*3], x1 = x[32+u*3+1], x2 = x[32+u*3+2];
        float o0=0.f,o1=0.f,o2=0.f;
        #pragma unroll
        for (int q = 0; q < 11; ++q) {
          float xv = (I_[q]==0) ? x0 : ((I_[q]==1) ? x1 : x2);
          float term = V_[q]*xv*sh[4+K_[q]];
          if (J_[q]==0) o0 += term; else if (J_[q]==1) o1 += term; else o2 += term;
        }
        const float sc = 0.2041241452319315f;
        STB(432 + u, o0*sc); STB(432 + 16 + u, o1*sc); STB(432 + 32 + u, o2*sc);
      }
      #pragma unroll
      for (int p = 0; p < 2; ++p) {           // T8
        int j = p*64 + lane;
        int e = j >> 3, u = j & 7;
        const float* x = xl + e*120; const float* sh = shl + e*12;
        short* tp = tls16 + e*600;
        float y0 = x[80+u*5], y1 = x[80+u*5+1], y2 = x[80+u*5+2],
              y3 = x[80+u*5+3], y4 = x[80+u*5+4];
        float o0=0.f,o1=0.f,o2=0.f;
        #pragma unroll
        for (int q = 0; q < 11; ++q) {
          float xv = (K_[q]==0) ? y0 : ((K_[q]==1) ? y1 : ((K_[q]==2) ? y2 :
                     ((K_[q]==3) ? y3 : y4)));
          float term = V_[q]*xv*sh[1+I_[q]];
          if (J_[q]==0) o0 += term; else if (J_[q]==1) o1 += term; else o2 += term;
        }
        const float sc = 0.2041241452319315f;
        STB(520 + u, o0*sc); STB(520 + 8 + u, o1*sc); STB(520 + 16 + u, o2*sc);
      }
    } else {
      #pragma unroll
      for (int p = 0; p < 8; ++p) {           // T1
        int j = p*64 + lane;
        int e = j >> 5, u = j & 31;
        const float* x = xl + e*120; const float* sh = shl + e*12;
        short* tp = tls16 + e*600;
        float xu = x[u];
        #pragma unroll
        for (int k = 0; k < 3; ++k)
          STB(32 + k*32 + u, xu*sh[1+k]*0.1178511301977579f);
      }
      #pragma unroll
      for (int p = 0; p < 8; ++p) {           // T2
        int j = p*64 + lane;
        int e = j >> 5, u = j & 31;
        const float* x = xl + e*120; const float* sh = shl + e*12;
        short* tp = tls16 + e*600;
        float xu = x[u];
        #pragma unroll
        for (int k = 0; k < 5; ++k)
          STB(128 + k*32 + u, xu*sh[4+k]*0.125f);
      }
    }
  }
  __syncthreads();   // t ready; xl region now dead -> reused as f16 w-tiles

  // ================= phase B: pipelined tiles (single MFMA_STORE instantiation) =================
  short* wl16 = wls16 + wv*1024;   // [16e][64c] f16, 16B-block swizzled by e&7

  // prologue: produce tile wv into wl
  MFMA_STORE(wv)

  for (int nt = wv; nt < 54; nt += 4) {
    const int m1 = TM1[nt], nk = TNK[nt], toff = TTOF[nt], tout = TOUT[nt];
    const int e = lane & 15, g = lane >> 4, e7 = e & 7;
    const short* wb = wl16 + e*64;

    // ---- branchless w-block indices; load current tile's w operands ----
    int b0 = (m1 == 32) ? (((g & 1) << 2) | ((g >> 1) << 1))
           : ((m1 == 16) ? (g << 1) : g);
    int b1 = (m1 == 8) ? (g + 4) : (b0 + 1);
    uint4 wr0 = *(const uint4*)&wb[((b0 ^ e7) << 3)];
    uint4 wr1 = *(const uint4*)&wb[((b1 ^ e7) << 3)];

    // ---- MFMA + store NEXT tile (hides w-load latency; loads precede stores) ----
    if (nt + 4 < 54) { MFMA_STORE(nt + 4) }

    // ---- compute current tile ----
    if (m1 == 32) {
      if (nk == 1)      COMP32(1)
      else if (nk == 3) COMP32(3)
      else              COMP32(5)
    } else if (m1 == 16) {
      if (nk == 1)      COMP16(1)
      else if (nk == 3) COMP16(3)
      else              COMP16(5)
    } else {
      if (nk == 1)      COMP8(1)
      else if (nk == 3) COMP8(3)
      else              COMP8(5)
    }
  }

  __syncthreads();
  // coalesced msg1 write: block's 16 edges are 1920 contiguous floats
  const float s = 0.3162277660168379f;
  for (int i = tid; i < 1920; i += 256) {
    int e = i / 120, c = i - e*120;
    msg1[(size_t)e0*120 + i] = msgl[e*121 + c] * s;
  }
}

// ================= output: dst-CSR msg1 aggregation + self-connection (2 nodes/block) =============
__global__ void __launch_bounds__(256) k_out(
    const float* __restrict__ msg1,
    const int* __restrict__ start2, const int* __restrict__ perm2,
    const float* __restrict__ node1,
    const float* __restrict__ sc0e, const float* __restrict__ sc1o,
    const float* __restrict__ sc2e, float* __restrict__ out) {
  __shared__ float x[2][120];
  int sub = threadIdx.x >> 7, t = threadIdx.x & 127;
  int n = blockIdx.x*2 + sub;                 // NN=5000 even: always < NN
  if (t < 120) x[sub][t] = node1[(size_t)n*120 + t];
  __syncthreads();
  if (t >= 120) return;
  float v = 0.f;
  const int s0 = start2[n], s1 = start2[n+1];
  for (int idx = s0; idx < s1; ++idx)
    v += msg1[(size_t)perm2[idx]*120 + t];
  if (t < 32) {
    float s = 0.f;
    for (int u = 0; u < 32; ++u) s += x[sub][u]*sc0e[u*32 + t];
    v += s * 0.1767766952966369f;
  } else if (t < 80) {
    int jj = t - 32, vv = jj/3, k = jj - vv*3;
    float s = 0.f;
    for (int u = 0; u < 16; ++u) s += x[sub][32 + u*3 + k]*sc1o[u*16 + vv];
    v += s * 0.25f;
  } else {
    int jj = t - 80, vv = jj/5, k = jj - vv*5;
    float s = 0.f;
    for (int u = 0; u < 8; ++u) s += x[sub][80 + u*5 + k]*sc2e[u*8 + vv];
    v += s * 0.3535533905932738f;
  }
  out[(size_t)n*120 + t] = v;
}

// ---------------- launch ----------------
extern "C" void kernel_launch(void* const* d_in, const int* in_sizes, int n_in,
                              void* d_out, int out_size, void* d_ws, size_t ws_size,
                              hipStream_t stream) {
  const float* embed   = (const float*)d_in[1];
  const float* rad_w1  = (const float*)d_in[2];
  const float* rad_b1  = (const float*)d_in[3];
  const float* rad_w2  = (const float*)d_in[4];
  const float* rad_b2  = (const float*)d_in[5];
  const float* wnn0_w1 = (const float*)d_in[6];
  const float* wnn0_w2 = (const float*)d_in[7];
  const float* wnn1_w1 = (const float*)d_in[8];
  const float* wnn1_w2 = (const float*)d_in[9];
  const float* sc0_0e  = (const float*)d_in[10];
  const float* sc1_0e  = (const float*)d_in[11];
  const float* sc1_1o  = (const float*)d_in[12];
  const float* sc1_2e  = (const float*)d_in[13];
  const float* edge_vec = (const float*)d_in[14];
  const float* edge_len = (const float*)d_in[15];
  const int*  anum    = (const int*)d_in[16];
  const int*  ei      = (const int*)d_in[17];

  float* ws = (float*)d_ws;
  float* shbuf = ws;                        // 600000
  float* bc    = ws + 600000;               // 400000
  bf16*  q1b   = (bf16*)(ws + 1000000);     // 1.6M f-slots
  float* node0 = ws + 2600000;              // 320000
  bf16*  node0b= (bf16*)(ws + 2920000);     // 160000 f-slots
  bf16*  W0rtb = (bf16*)(ws + 3080000);     // 114688 f-slots
  bf16*  W2t   = (bf16*)(ws + 3194688);     // 110592 f-slots
  bf16*  Mbb   = (bf16*)(ws + 3305280);     // 4096 f-slots
  float* bias0 = ws + 3309376;              // 64
  float* bias1 = ws + 3309440;              // 64
  int*   hist   = (int*)(ws + 3309504);     // 5000 (memset covers hist..cursor2)
  int*   cursor = (int*)(ws + 3314504);     // 5000
  int*   hist2  = (int*)(ws + 3319504);     // 5000
  int*   cursor2= (int*)(ws + 3324504);     // 5000
  int*   start  = (int*)(ws + 3329504);     // 5008
  int*   start2 = (int*)(ws + 3334512);     // 5008
  int*   perm   = (int*)(ws + 3339520);     // 50000
  int*   perm2  = (int*)(ws + 3389520);     // 50000
  float* node1 = ws + 3439520;              // 600000
  float* msg1  = ws + 4039520;              // 6000000 (50000 x 120)
  // layer-0-only region:
  float* q0    = ws + 10039520;             // 3200000
  float* zbuf  = ws + 13239520;             // 2800000 (50000 x 56)
  bf16*  G0    = (bf16*)(ws + 16039520);    // 17.92M bf16

  hipMemsetAsync(hist, 0, 20000*sizeof(int), stream);   // hist, cursor, hist2, cursor2

  k_setup<<<3222, 256, 0, stream>>>(edge_vec, edge_len, shbuf, bc,
                                    rad_w2, rad_b2, wnn0_w1, wnn1_w1, Mbb, bias0, bias1,
                                    embed, anum, node0, node0b,
                                    wnn0_w2, W0rtb, wnn1_w2, W2t, ei, hist, hist2);
  k_mid<<<1565, 256, 0, stream>>>(bc, rad_w1, rad_b1, Mbb, bias0, bias1,
                                  q0, q1b, hist, start, hist2, start2);
  k_pre0<<<196 + 14*157, 256, 0, stream>>>(ei, start, cursor, perm,
                                           start2, cursor2, perm2,
                                           node0b, W0rtb, G0);
  k_msg0z<<<NN, 256, 0, stream>>>(q0, G0, start, perm, zbuf);
  k_agg0<<<NN/2, 256, 0, stream>>>(zbuf, shbuf, start2, perm2, node0, sc0_0e, node1);

  // fused layer-1: GEMM + tensor-product contraction, no wbuf intermediate
  k_fuse<<<3125, 256, 0, stream>>>(q1b, W2t, node1, shbuf, ei, msg1);

  k_out<<<NN/2, 256, 0, stream>>>(msg1, start2, perm2, node1, sc1_0e, sc1_1o, sc1_2e, (float*)d_out);
}

// Round 13
// 391.959 us; speedup vs baseline: 1.0335x; 1.0335x over previous
//
#include <hip/hip_runtime.h>
#include <hip/hip_bf16.h>
#include <math.h>

#define E_EDGES 50000
#define NN 5000

typedef __hip_bfloat16 bf16;
typedef __attribute__((ext_vector_type(8))) short short8;
typedef __attribute__((ext_vector_type(4))) float f32x4;
typedef __attribute__((ext_vector_type(2))) _Float16 h2;

__device__ __forceinline__ float b2f(bf16 v) { return __bfloat162float(v); }
__device__ __forceinline__ float siluf(float x) { return x / (1.0f + __expf(-x)); }
__device__ __forceinline__ float us2f(unsigned short u) {
  union { unsigned int i; float f; } c; c.i = ((unsigned int)u) << 16; return c.f;
}

__device__ __forceinline__ float fdot2f(h2 a, h2 b, float c) {
#if __has_builtin(__builtin_amdgcn_fdot2)
  return __builtin_amdgcn_fdot2(a, b, c, false);
#else
  return c + (float)a.x*(float)b.x + (float)a.y*(float)b.y;
#endif
}
__device__ __forceinline__ float dot8h(uint4 w, uint4 t, float acc) {
  acc = fdot2f(__builtin_bit_cast(h2, w.x), __builtin_bit_cast(h2, t.x), acc);
  acc = fdot2f(__builtin_bit_cast(h2, w.y), __builtin_bit_cast(h2, t.y), acc);
  acc = fdot2f(__builtin_bit_cast(h2, w.z), __builtin_bit_cast(h2, t.z), acc);
  acc = fdot2f(__builtin_bit_cast(h2, w.w), __builtin_bit_cast(h2, t.w), acc);
  return acc;
}

// ================= merged setup: prep(+hists) | fuse->Mbb | embed | w0rtb | w2t =================
__global__ void __launch_bounds__(256) k_setup(
    const float* __restrict__ evec, const float* __restrict__ elen,
    float* __restrict__ shb, float* __restrict__ bc,
    const float* __restrict__ w2, const float* __restrict__ b2,
    const float* __restrict__ w01, const float* __restrict__ w11,
    bf16* __restrict__ Mbb,
    float* __restrict__ bias0, float* __restrict__ bias1,
    const float* __restrict__ emb, const int* __restrict__ an,
    float* __restrict__ node0, bf16* __restrict__ node0b,
    const float* __restrict__ w0, bf16* __restrict__ W0rtb,
    const float* __restrict__ w1w2, bf16* __restrict__ W2t,
    const int* __restrict__ ei, int* __restrict__ hist, int* __restrict__ hist2) {
  const int b = blockIdx.x, tid = threadIdx.x;
  if (b < 196) {                      // ---- prep (sh + basis*cutoff) + src/dst histograms
    int e = b*256 + tid;
    if (e >= E_EDGES) return;
    atomicAdd(&hist[ei[e]], 1);
    atomicAdd(&hist2[ei[E_EDGES + e]], 1);
    float x = evec[3*e+0], y = evec[3*e+1], z = evec[3*e+2];
    float r = elen[e];
    float inv = 1.0f / (r + 1e-8f);
    float ux = x*inv, uy = y*inv, uz = z*inv;
    const float s3 = 1.7320508075688772f, s5 = 2.2360679774997896f, s15 = 3.8729833462074170f;
    float* sh = shb + (size_t)e*12;
    sh[0] = 1.0f;
    sh[1] = s3*uy; sh[2] = s3*uz; sh[3] = s3*ux;
    sh[4] = s15*ux*uy; sh[5] = s15*uy*uz; sh[6] = 0.5f*s5*(3.0f*uz*uz - 1.0f);
    sh[7] = s15*ux*uz; sh[8] = 0.5f*s15*(ux*ux - uy*uy);
    sh[9] = 0.f; sh[10] = 0.f; sh[11] = 0.f;
    float rr = fmaxf(r, 1e-8f);
    const float pi = 3.14159265358979f;
    float xr = r * 0.2f;
    float cut = (xr < 1.0f) ? 0.5f*(1.0f + cosf(pi*xr)) : 0.0f;
    float fb = pi * 0.2f;
    for (int k = 1; k <= 8; ++k)
      bc[(size_t)e*8 + (k-1)] = sinf(fb*(float)k*r)/rr * cut;
  } else if (b < 212) {               // ---- fuse rad_w2 into wnn*_w1 -> Mbb (B-layout bf16)
    int i = (b-196)*256 + tid;        // 4096
    int hh = i >> 6, c = i & 63;
    float a0 = 0.f, a1 = 0.f;
    for (int j = 0; j < 64; ++j) {
      float wv = w2[hh*64 + j];
      a0 += wv * w01[j*64 + c];
      a1 += wv * w11[j*64 + c];
    }
    Mbb[(size_t)c*64 + hh]        = __float2bfloat16(a0);
    Mbb[(size_t)(64 + c)*64 + hh] = __float2bfloat16(a1);
    if (hh == 0) {
      float s0 = 0.f, s1 = 0.f;
      for (int j = 0; j < 64; ++j) {
        s0 += b2[j] * w01[j*64 + c];
        s1 += b2[j] * w11[j*64 + c];
      }
      bias0[c] = s0;
      bias1[c] = s1;
    }
  } else if (b < 1462) {              // ---- embed (320000 exact): fp32 + bf16 copies
    int i = (b-212)*256 + tid;
    int n = i >> 6, c = i & 63;
    float v = emb[an[n]*64 + c];
    node0[i] = v;
    node0b[i] = __float2bfloat16(v);
  } else if (b < 2358) {              // ---- W0rtb[col*64+u] bf16, col = h*56+vp (229376 exact)
    int idx = (b-1462)*256 + tid;
    int col = idx >> 6, u = idx & 63;
    int hh = col / 56, vp = col - hh*56;
    int boff, m3, v;
    if (vp < 32)      { boff = 0;    m3 = 32; v = vp; }
    else if (vp < 48) { boff = 2048; m3 = 16; v = vp - 32; }
    else              { boff = 3072; m3 = 8;  v = vp - 48; }
    W0rtb[idx] = __float2bfloat16(w0[hh*3584 + boff + u*m3 + v]);
  } else {                            // ---- w2t transpose + per-path [v][u] permute
    int idx = (b-2358)*256 + tid;     // 221184 exact
    int nn = idx >> 6, k = idx & 63;
    int p, loc;
    if (nn < 1024)      { p=0;  loc=nn;      }
    else if (nn < 1536) { p=1;  loc=nn-1024; }
    else if (nn < 1792) { p=2;  loc=nn-1536; }
    else if (nn < 2048) { p=3;  loc=nn-1792; }
    else if (nn < 2560) { p=4;  loc=nn-2048; }
    else if (nn < 2688) { p=5;  loc=nn-2560; }
    else if (nn < 2944) { p=6;  loc=nn-2688; }
    else if (nn < 3008) { p=7;  loc=nn-2944; }
    else if (nn < 3136) { p=8;  loc=nn-3008; }
    else if (nn < 3392) { p=9;  loc=nn-3136; }
    else                { p=10; loc=nn-3392; }
    const int M1s[11] = {32,32,32,16,16,16,16,8,8,8,8};
    const int M3s[11] = {32,16,8,16,32,8,16,8,16,32,8};
    int m1 = M1s[p], m3 = M3s[p];
    int v = loc / m1, u = loc - v*m1;
    int src = (nn - loc) + u*m3 + v;
    W2t[idx] = __float2bfloat16(w1w2[(size_t)k*3456 + src]);
  }
}

// ================= k_mid: rad (h-VALU + MFMA q-GEMM) | scan x2 =================
__global__ void __launch_bounds__(256) k_mid(
    const float* __restrict__ bc,
    const float* __restrict__ w1, const float* __restrict__ b1,
    const bf16* __restrict__ Mbb,
    const float* __restrict__ bias0, const float* __restrict__ bias1,
    float* __restrict__ q0, bf16* __restrict__ q1b,
    const int* __restrict__ hist, int* __restrict__ start,
    const int* __restrict__ hist2, int* __restrict__ start2) {
  __shared__ float smem[1024];
  __shared__ __align__(16) short sHb[2048];
  const int tid = threadIdx.x;
  const int b = blockIdx.x;
  if (b < 1563) {
    float* sW1 = smem;
    float* sB  = smem + 512;
    float* sb0 = smem + 576;
    float* sb1 = smem + 640;
    float* sBC = smem + 704;
    const int j = tid >> 6, m = tid & 63;
    for (int i = tid; i < 512; i += 256) sW1[i] = w1[i];
    if (tid < 64) { sB[tid] = b1[tid]; sb0[tid] = bias0[tid]; sb1[tid] = bias1[tid]; }
    {
      int e = b*32 + (tid >> 3);
      int k = tid & 7;
      int eL = e < E_EDGES ? e : E_EDGES-1;
      sBC[tid] = bc[(size_t)eL*8 + k];
    }
    __syncthreads();
    #pragma unroll
    for (int g = 0; g < 8; ++g) {
      int el = g*4 + j;
      float t = sB[m];
      #pragma unroll
      for (int k = 0; k < 8; ++k) t += sBC[el*8+k]*sW1[k*64+m];
      bf16 hv = __float2bfloat16(siluf(t));
      sHb[el*64 + m] = *(short*)&hv;
    }
    __syncthreads();
    const int w = tid >> 6, lane = tid & 63;
    const int row16 = lane & 15, quad = lane >> 4;
    const int mtile = w & 1, cg = w >> 1;
    const short* ap = sHb + (mtile*16 + row16)*64 + quad*8;
    short8 a0 = *(const short8*)ap;
    short8 a1 = *(const short8*)(ap + 32);
    f32x4 acc[4] = {};
    #pragma unroll
    for (int ni = 0; ni < 4; ++ni) {
      const short* bp = (const short*)Mbb + (size_t)(cg*64 + ni*16 + row16)*64 + quad*8;
      short8 b0 = *(const short8*)bp;
      short8 b1v = *(const short8*)(bp + 32);
      acc[ni] = __builtin_amdgcn_mfma_f32_16x16x32_bf16(a0, b0, acc[ni], 0,0,0);
      acc[ni] = __builtin_amdgcn_mfma_f32_16x16x32_bf16(a1, b1v, acc[ni], 0,0,0);
    }
    const float* bias = cg ? sb1 : sb0;
    #pragma unroll
    for (int ni = 0; ni < 4; ++ni) {
      int c = ni*16 + row16;
      float bv = bias[c];
      #pragma unroll
      for (int r = 0; r < 4; ++r) {
        int e = b*32 + mtile*16 + quad*4 + r;
        if (e < E_EDGES) {
          float val = siluf(acc[ni][r] + bv);
          if (cg == 0) q0[(size_t)e*64 + c] = val;
          else         q1b[(size_t)e*64 + c] = __float2bfloat16(val);
        }
      }
    }
  } else {
    const int* h = (b == 1563) ? hist : hist2;
    int* st      = (b == 1563) ? start : start2;
    int* sp = (int*)smem;
    int base = tid*20;
    int localsum = 0;
    for (int i = 0; i < 20; ++i) { int jj = base+i; localsum += (jj < NN) ? h[jj] : 0; }
    sp[tid] = localsum;
    __syncthreads();
    if (tid == 0) {
      int acc = 0;
      for (int i = 0; i < 256; ++i) { int t = sp[i]; sp[i] = acc; acc += t; }
    }
    __syncthreads();
    int run = sp[tid];
    for (int i = 0; i < 20; ++i) {
      int jj = base+i;
      if (jj < NN) { st[jj] = run; run += h[jj]; }
    }
    if (tid == 255) st[NN] = run;
  }
}

// ================= k_pre0: scat (src+dst CSR) | G0 MFMA GEMM (flattened) =================
__global__ void __launch_bounds__(256) k_pre0(
    const int* __restrict__ ei,
    const int* __restrict__ start, int* __restrict__ cursor, int* __restrict__ perm,
    const int* __restrict__ start2, int* __restrict__ cursor2, int* __restrict__ perm2,
    const bf16* __restrict__ A, const bf16* __restrict__ B, bf16* __restrict__ out) {
  __shared__ short lds[4][32*64];
  const int b = blockIdx.x, tid = threadIdx.x;
  if (b < 196) {
    int e = b*256 + tid;
    if (e >= E_EDGES) return;
    int src = ei[e];
    perm[start[src] + atomicAdd(&cursor[src], 1)] = e;
    int dst = ei[E_EDGES + e];
    perm2[start2[dst] + atomicAdd(&cursor2[dst], 1)] = e;
  } else {
    const int bb = b - 196;           // 14 x 157 blocks
    const int wid = tid >> 6, lane = tid & 63;
    const int nt = (bb % 14)*4 + wid;
    const int r0 = (bb / 14)*32;
    const int row16 = lane & 15, quad = lane >> 4;
    short8 a[2][2];
    #pragma unroll
    for (int mi = 0; mi < 2; ++mi) {
      int r = r0 + mi*16 + row16;
      int rg = (r < NN) ? r : 0;
      const short* ap = (const short*)A + (size_t)rg*64 + quad*8;
      a[mi][0] = *(const short8*)(ap);
      a[mi][1] = *(const short8*)(ap + 32);
    }
    if (nt < 56) {
      f32x4 acc[4][2] = {};
      #pragma unroll
      for (int ni = 0; ni < 4; ++ni) {
        int col = nt*64 + ni*16 + row16;
        const short* bp = (const short*)B + (size_t)col*64 + quad*8;
        short8 b0 = *(const short8*)(bp);
        short8 b1 = *(const short8*)(bp + 32);
        #pragma unroll
        for (int mi = 0; mi < 2; ++mi) {
          acc[ni][mi] = __builtin_amdgcn_mfma_f32_16x16x32_bf16(a[mi][0], b0, acc[ni][mi], 0,0,0);
          acc[ni][mi] = __builtin_amdgcn_mfma_f32_16x16x32_bf16(a[mi][1], b1, acc[ni][mi], 0,0,0);
        }
      }
      #pragma unroll
      for (int ni = 0; ni < 4; ++ni)
        #pragma unroll
        for (int mi = 0; mi < 2; ++mi)
          #pragma unroll
          for (int rr = 0; rr < 4; ++rr) {
            bf16 hv = __float2bfloat16(acc[ni][mi][rr]);
            lds[wid][(mi*16 + quad*4 + rr)*64 + ni*16 + row16] = *(short*)&hv;
          }
    }
    __syncthreads();
    if (nt < 56) {
      #pragma unroll
      for (int it = 0; it < 4; ++it) {
        int unit = it*64 + lane;
        int rrow = unit >> 3;
        int cu = (unit & 7) * 8;
        int r = r0 + rrow;
        if (r < NN)
          *(uint4*)((short*)out + (size_t)r*3584 + nt*64 + cu) =
              *(const uint4*)&lds[wid][rrow*64 + cu];
      }
    }
  }
}

// ================= layer-0 z: per-src-node; G0 row in LDS; z -> zbuf (no atomics) =================
__global__ void __launch_bounds__(256) k_msg0z(
    const float* __restrict__ q0, const bf16* __restrict__ G0,
    const int* __restrict__ start, const int* __restrict__ perm,
    float* __restrict__ zbuf) {
  __shared__ uint4 g4[448];
  __shared__ float sq[4][64];
  const int n = blockIdx.x;
  const int tid = threadIdx.x;
  const int wv = tid >> 6, lane = tid & 63;
  const uint4* gr = (const uint4*)(G0 + (size_t)n*3584);
  for (int i = tid; i < 448; i += 256) g4[i] = gr[i];
  const int s0 = start[n], s1 = start[n+1];
  __syncthreads();
  const short* gs = (const short*)g4;
  for (int base = s0; base < s1; base += 4) {
    int idx = base + wv;
    if (idx < s1) {
      int e = perm[idx];
      sq[wv][lane] = q0[(size_t)e*64 + lane];
      float z = 0.f;
      if (lane < 56) {
        #pragma unroll
        for (int h = 0; h < 64; ++h)
          z += sq[wv][h]*us2f((unsigned short)gs[h*56 + lane]);
        zbuf[(size_t)e*56 + lane] = z;
      }
    }
  }
}

// ================= layer-0 aggregate (dst-CSR) + self-connection -> node1 =================
__global__ void k_agg0(const float* __restrict__ zbuf, const float* __restrict__ shb,
                       const int* __restrict__ start2, const int* __restrict__ perm2,
                       const float* __restrict__ node0, const float* __restrict__ sc00,
                       float* __restrict__ node1) {
  __shared__ float n0[64];
  int n = blockIdx.x, tid = threadIdx.x;
  if (tid < 64) n0[tid] = node0[(size_t)n*64 + tid];
  __syncthreads();
  if (tid >= 120) return;
  int c = tid, zi, shi;
  if (c < 32)      { zi = c; shi = -1; }
  else if (c < 80) { int j = c-32, v = j/3, k = j - v*3; zi = 32 + v; shi = 1 + k; }
  else             { int j = c-80, v = j/5, k = j - v*5; zi = 48 + v; shi = 4 + k; }
  float acc = 0.f;
  const int s0 = start2[n], s1 = start2[n+1];
  for (int idx = s0; idx < s1; ++idx) {
    int e = perm2[idx];
    float z = zbuf[(size_t)e*56 + zi];
    acc += (shi < 0) ? z : z*shb[(size_t)e*12 + shi];
  }
  acc *= 0.125f * 0.3162277660168379f;
  if (c < 32) {
    float s = 0.f;
    for (int u = 0; u < 64; ++u) s += n0[u]*sc00[u*32 + c];
    acc += s * 0.125f;
    acc = siluf(acc);
  }
  node1[(size_t)n*120 + c] = acc;
}

// ================= fused layer-1: per-edge weight GEMM (MFMA) + TP contraction =================
// v13 = v8 exactly (session best: 393.4us total, k_fuse 210us): branchless w-loads,
// single MFMA_STORE in loop, f16 w/t, fdot2, launch_bounds(256,4). Converged config:
// 8-wave (v9/v10), t-prefetch (v11), aux repack (v12) all neutral-or-worse.

// tile tables (54 tiles of 64 cols over the 11 paths)
static __device__ const int TM1[54] = {
  32,32,32,32,32,32,32,32,32,32,32,32,32,32,32,32,
  32,32,32,32,32,32,32,32,
  32,32,32,32,
  16,16,16,16,
  16,16,16,16,16,16,16,16,
  16,16,
  16,16,16,16,
  8,
  8,8,
  8,8,8,8,
  8};
static __device__ const int TNK[54] = {
  1,1,1,1,1,1,1,1,1,1,1,1,1,1,1,1,
  3,3,3,3,3,3,3,3,
  5,5,5,5,
  3,3,3,3,
  1,1,1,1,1,1,1,1,
  5,5,
  3,3,3,3,
  5,
  3,3,
  1,1,1,1,
  5};
static __device__ const int TTOF[54] = {
  0,0,0,0,0,0,0,0,0,0,0,0,0,0,0,0,
  32,32,32,32,32,32,32,32,
  128,128,128,128,
  288,288,288,288,
  336,336,336,336,336,336,336,336,
  352,352,
  432,432,432,432,
  480,
  520,520,
  544,544,544,544,
  552};
static __device__ const int TOUT[54] = {
  0,2,4,6,8,10,12,14,16,18,20,22,24,26,28,30,
  32,38,44,50,56,62,68,74,
  80,90,100,110,
  32,44,56,68,
  0,4,8,12,16,20,24,28,
  80,100,
  32,44,56,68,
  80,
  32,56,
  0,8,16,24,
  80};

#define STB(ST, VAL) { _Float16 hv_ = (_Float16)(VAL); tp[ST] = *(short*)&hv_; }

// store full 64-col f16 w-tile, 16B-block swizzled by e&7
#define STORE_WL(ACC) { \
    _Pragma("unroll") \
    for (int ni_ = 0; ni_ < 4; ++ni_) { \
      _Pragma("unroll") \
      for (int r_ = 0; r_ < 4; ++r_) { \
        int e_ = quad*4 + r_; \
        int c_ = ni_*16 + row16; \
        _Float16 hv_ = (_Float16)((ACC)[ni_][r_]); \
        wl16[e_*64 + ((((c_>>3) ^ (e_&7))<<3) | (c_&7))] = *(short*)&hv_; \
      } \
    } }

// MFMA tile (NTT), prefetch frags for NTT+4, store f16 tile
#define MFMA_STORE(NTT) { \
    f32x4 acc_[4] = {}; \
    _Pragma("unroll") \
    for (int ni_ = 0; ni_ < 4; ++ni_) { \
      acc_[ni_] = __builtin_amdgcn_mfma_f32_16x16x32_bf16(a0, bf0[ni_], acc_[ni_], 0,0,0); \
      acc_[ni_] = __builtin_amdgcn_mfma_f32_16x16x32_bf16(a1, bf1[ni_], acc_[ni_], 0,0,0); \
    } \
    if ((NTT) + 4 < 54) { \
      _Pragma("unroll") \
      for (int ni_ = 0; ni_ < 4; ++ni_) { \
        const short* bp_ = (const short*)W2t + (size_t)(((NTT)+4)*64 + ni_*16 + row16)*64 + quad*8; \
        bf0[ni_] = *(const short8*)bp_; \
        bf1[ni_] = *(const short8*)(bp_ + 32); \
      } \
    } \
    STORE_WL(acc_) }

// compute bodies (t loads + dots + atomics fully inside each branch)
#define COMP32(NKC) { \
    const short* tb = tls16 + e*600 + toff + ((g >> 1) << 4); \
    _Pragma("unroll") \
    for (int k_ = 0; k_ < NKC; ++k_) { \
      uint4 t0 = *(const uint4*)&tb[k_*32]; \
      uint4 t1 = *(const uint4*)&tb[k_*32 + 8]; \
      float ak = dot8h(wr0, t0, 0.f); \
      ak = dot8h(wr1, t1, ak); \
      ak += __shfl_xor(ak, 32); \
      if (g < 2) atomicAdd(&msgl[e*121 + tout + (g&1)*(NKC) + k_], ak); \
    } }
#define COMP16(NKC) { \
    const short* tb = tls16 + e*600 + toff; \
    _Pragma("unroll") \
    for (int k_ = 0; k_ < NKC; ++k_) { \
      uint4 t0 = *(const uint4*)&tb[k_*16]; \
      uint4 t1 = *(const uint4*)&tb[k_*16 + 8]; \
      float ak = dot8h(wr0, t0, 0.f); \
      ak = dot8h(wr1, t1, ak); \
      atomicAdd(&msgl[e*121 + tout + g*(NKC) + k_], ak); \
    } }
#define COMP8(NKC) { \
    const short* tb = tls16 + e*600 + toff; \
    _Pragma("unroll") \
    for (int k_ = 0; k_ < NKC; ++k_) { \
      uint4 t0 = *(const uint4*)&tb[k_*8]; \
      float ak = dot8h(wr0, t0, 0.f); \
      atomicAdd(&msgl[e*121 + tout + g*(NKC) + k_], ak); \
      float ak2 = dot8h(wr1, t0, 0.f); \
      atomicAdd(&msgl[e*121 + tout + (g+4)*(NKC) + k_], ak2); \
    } }

__global__ void __launch_bounds__(256, 4) k_fuse(
    const bf16* __restrict__ q1b, const bf16* __restrict__ W2t,
    const float* __restrict__ node1, const float* __restrict__ shb,
    const int* __restrict__ ei, float* __restrict__ msg1) {
  __shared__ __align__(16) short tls16[16*600];  // 19,200 B: t f16, [k][u] per path
  __shared__ __align__(16) short wls16[4*1024];  // 8,192 B: phase A x[16][120] fp32 / phase B f16 w-tiles
  __shared__ float msgl[16*121];                 // 7,744 B (odd word stride)
  __shared__ float shl[16*12];                   // 768 B
  float* xl = (float*)wls16;

  const int tid = threadIdx.x;
  const int wv = tid >> 6, lane = tid & 63;
  const int e0 = blockIdx.x * 16;               // 3125 * 16 == 50000 exact
  const int row16 = lane & 15, quad = lane >> 4;

  // ---- cooperative load: x (node1[src]) + sh; zero msg ----
  {
    int e = tid >> 4, c0 = tid & 15;
    int src = ei[e0 + e];
    const float* xp = node1 + (size_t)src*120;
    for (int c = c0; c < 120; c += 16) xl[e*120 + c] = xp[c];
    if (c0 < 12) shl[e*12 + c0] = shb[(size_t)(e0+e)*12 + c0];
  }
  for (int i = tid; i < 1936; i += 256) msgl[i] = 0.f;

  // ---- A-fragments + first-tile B-fragments (issued before phase A to hide latency) ----
  const short* ap = (const short*)q1b + (size_t)(e0 + row16)*64 + quad*8;
  short8 a0 = *(const short8*)ap;
  short8 a1 = *(const short8*)(ap + 32);
  short8 bf0[4], bf1[4];
  #pragma unroll
  for (int ni = 0; ni < 4; ++ni) {
    const short* bp = (const short*)W2t + (size_t)(wv*64 + ni*16 + row16)*64 + quad*8;
    bf0[ni] = *(const short8*)bp;
    bf1[ni] = *(const short8*)(bp + 32);
  }

  __syncthreads();

  // ================= phase A: type-per-wave, all 64 lanes uniform per pass =================
  {
    const float Av = 0.3162277660168379f, Bc = 0.1825741858350554f, B2 = 0.3651483716701107f;
    const int I_[11] = {0,2,0,1,1,2, 0,1,2, 0,2};
    const int J_[11] = {2,0,1,0,2,1, 0,1,2, 0,2};
    const int K_[11] = {0,0,1,1,3,3, 2,2,2, 4,4};
    const float V_[11] = {Av,Av,Av,Av,Av,Av, -Bc,B2,-Bc, -Av,Av};
    const float P = 0.2390457218668787f, Q = 0.2070196678027063f, R = 0.1195228609334394f;
    const int I2_[25] = {0,0,2, 0,0,1,1,3,3, 1,1,2, 1,1,4, 2, 2,3,3, 2,4,4, 3,3,4};
    const int J2_[25] = {0,2,0, 1,3,0,3,0,1, 1,2,1, 1,4,1, 2, 3,2,3, 4,2,4, 3,4,3};
    const int K2_[25] = {2,0,0, 3,1,3,0,1,0, 2,1,1, 4,1,1, 2, 3,3,2, 4,4,2, 4,3,3};
    const float V2_[25] = {P,P,P, -Q,-Q,-Q,-Q,-Q,-Q, -R,-R,-R, Q,Q,Q, -P,
                           -R,-R,-R, P,P,P, -Q,-Q,-Q};

    if (wv == 0) {
      #pragma unroll
      for (int p = 0; p < 12; ++p) {          // T3
        int j = p*64 + lane;
        int e = j/48, r = j - e*48;
        int u = r/3, k = r - u*3;
        const float* x = xl + e*120;
        short* tp = tls16 + e*600;
        STB(288 + k*16 + u, x[32+u*3+k]*0.1178511301977579f);
      }
      #pragma unroll
      for (int p = 0; p < 4; ++p) {           // T4
        int j = p*64 + lane;
        int e = j >> 4, u = j & 15;
        const float* x = xl + e*120; const float* sh = shl + e*12;
        short* tp = tls16 + e*600;
        STB(336 + u, (x[32+u*3]*sh[1] + x[32+u*3+1]*sh[2] + x[32+u*3+2]*sh[3])
                     * 0.0771516749810460f);
      }
      #pragma unroll
      for (int p = 0; p < 2; ++p) {           // T10
        int j = p*64 + lane;
        int e = j >> 3, u = j & 7;
        const float* x = xl + e*120; const float* sh = shl + e*12;
        short* tp = tls16 + e*600;
        float y0 = x[80+u*5], y1 = x[80+u*5+1], y2 = x[80+u*5+2],
              y3 = x[80+u*5+3], y4 = x[80+u*5+4];
        float o0=0.f,o1=0.f,o2=0.f,o3=0.f,o4=0.f;
        #pragma unroll
        for (int q = 0; q < 25; ++q) {
          float xv = (I2_[q]==0) ? y0 : ((I2_[q]==1) ? y1 : ((I2_[q]==2) ? y2 :
                     ((I2_[q]==3) ? y3 : y4)));
          float term = V2_[q]*xv*sh[4+J2_[q]];
          if (K2_[q]==0) o0 += term; else if (K2_[q]==1) o1 += term;
          else if (K2_[q]==2) o2 += term; else if (K2_[q]==3) o3 += term; else o4 += term;
        }
        const float sc = 0.2795084971874737f;
        STB(552 + u, o0*sc); STB(552 + 8 + u, o1*sc); STB(552 + 16 + u, o2*sc);
        STB(552 + 24 + u, o3*sc); STB(552 + 32 + u, o4*sc);
      }
    } else if (wv == 1) {
      #pragma unroll
      for (int p = 0; p < 10; ++p) {          // T7
        int j = p*64 + lane;
        int e = j/40, r = j - e*40;
        int u = r/5, k = r - u*5;
        const float* x = xl + e*120;
        short* tp = tls16 + e*600;
        STB(480 + k*8 + u, x[80+u*5+k]*0.125f);
      }
      #pragma unroll
      for (int p = 0; p < 4; ++p) {           // T5
        int j = p*64 + lane;
        int e = j >> 4, u = j & 15;
        const float* x = xl + e*120; const float* sh = shl + e*12;
        short* tp = tls16 + e*600;
        float x0 = x[32+u*3], x1 = x[32+u*3+1], x2 = x[32+u*3+2];
        float o0=0.f,o1=0.f,o2=0.f,o3=0.f,o4=0.f;
        #pragma unroll
        for (int q = 0; q < 11; ++q) {
          float xv = (I_[q]==0) ? x0 : ((I_[q]==1) ? x1 : x2);
          float term = V_[q]*xv*sh[1+J_[q]];
          if (K_[q]==0) o0 += term; else if (K_[q]==1) o1 += term;
          else if (K_[q]==2) o2 += term; else if (K_[q]==3) o3 += term; else o4 += term;
        }
        const float sc = 0.2795084971874737f;
        STB(352 + u, o0*sc); STB(352 + 16 + u, o1*sc); STB(352 + 32 + u, o2*sc);
        STB(352 + 48 + u, o3*sc); STB(352 + 64 + u, o4*sc);
      }
      #pragma unroll
      for (int p = 0; p < 2; ++p) {           // T9
        int j = p*64 + lane;
        int e = j >> 3, u = j & 7;
        const float* x = xl + e*120; const float* sh = shl + e*12;
        short* tp = tls16 + e*600;
        STB(544 + u, (x[80+u*5]*sh[4] + x[80+u*5+1]*sh[5] + x[80+u*5+2]*sh[6]
                    + x[80+u*5+3]*sh[7] + x[80+u*5+4]*sh[8]) * 0.0597614304667197f);
      }
    } else if (wv == 2) {
      #pragma unroll
      for (int p = 0; p < 8; ++p) {           // T0
        int j = p*64 + lane;
        int e = j >> 5, u = j & 31;
        const float* x = xl + e*120;
        short* tp = tls16 + e*600;
        STB(u, x[u] * 0.1336306209562122f);
      }
      #pragma unroll
      for (int p = 0; p < 4; ++p) {           // T6
        int j = p*64 + lane;
        int e = j >> 4, u = j & 15;
        const float* x = xl + e*120; const float* sh = shl + e*12;
        short* tp = tls16 + e*600;
        float x0 = x[32+u*3], x1 = x[32+u*3+1], x2 = x[32+u*3+2];
        float o0=0.f,o1=0.f,o2=0.f;
        #pragma unroll
        for (int q = 0; q < 11; ++q) {
          float xv = (I_[q]==0) ? x0 : ((I_[q]==1) ? x1 : x2);
          float term = V_[q]*xv*sh[4+K_[q]];
          if (J_[q]==0) o0 += term; else if (J_[q]==1) o1 += term; else o2 += term;
        }
        const float sc = 0.2041241452319315f;
        STB(432 + u, o0*sc); STB(432 + 16 + u, o1*sc); STB(432 + 32 + u, o2*sc);
      }
      #pragma unroll
      for (int p = 0; p < 2; ++p) {           // T8
        int j = p*64 + lane;
        int e = j >> 3, u = j & 7;
        const float* x = xl + e*120; const float* sh = shl + e*12;
        short* tp = tls16 + e*600;
        float y0 = x[80+u*5], y1 = x[80+u*5+1], y2 = x[80+u*5+2],
              y3 = x[80+u*5+3], y4 = x[80+u*5+4];
        float o0=0.f,o1=0.f,o2=0.f;
        #pragma unroll
        for (int q = 0; q < 11; ++q) {
          float xv = (K_[q]==0) ? y0 : ((K_[q]==1) ? y1 : ((K_[q]==2) ? y2 :
                     ((K_[q]==3) ? y3 : y4)));
          float term = V_[q]*xv*sh[1+I_[q]];
          if (J_[q]==0) o0 += term; else if (J_[q]==1) o1 += term; else o2 += term;
        }
        const float sc = 0.2041241452319315f;
        STB(520 + u, o0*sc); STB(520 + 8 + u, o1*sc); STB(520 + 16 + u, o2*sc);
      }
    } else {
      #pragma unroll
      for (int p = 0; p < 8; ++p) {           // T1
        int j = p*64 + lane;
        int e = j >> 5, u = j & 31;
        const float* x = xl + e*120; const float* sh = shl + e*12;
        short* tp = tls16 + e*600;
        float xu = x[u];
        #pragma unroll
        for (int k = 0; k < 3; ++k)
          STB(32 + k*32 + u, xu*sh[1+k]*0.1178511301977579f);
      }
      #pragma unroll
      for (int p = 0; p < 8; ++p) {           // T2
        int j = p*64 + lane;
        int e = j >> 5, u = j & 31;
        const float* x = xl + e*120; const float* sh = shl + e*12;
        short* tp = tls16 + e*600;
        float xu = x[u];
        #pragma unroll
        for (int k = 0; k < 5; ++k)
          STB(128 + k*32 + u, xu*sh[4+k]*0.125f);
      }
    }
  }
  __syncthreads();   // t ready; xl region now dead -> reused as f16 w-tiles

  // ================= phase B: pipelined tiles (single MFMA_STORE instantiation) =================
  short* wl16 = wls16 + wv*1024;   // [16e][64c] f16, 16B-block swizzled by e&7

  // prologue: produce tile wv into wl
  MFMA_STORE(wv)

  for (int nt = wv; nt < 54; nt += 4) {
    const int m1 = TM1[nt], nk = TNK[nt], toff = TTOF[nt], tout = TOUT[nt];
    const int e = lane & 15, g = lane >> 4, e7 = e & 7;
    const short* wb = wl16 + e*64;

    // ---- branchless w-block indices; load current tile's w operands ----
    int b0 = (m1 == 32) ? (((g & 1) << 2) | ((g >> 1) << 1))
           : ((m1 == 16) ? (g << 1) : g);
    int b1 = (m1 == 8) ? (g + 4) : (b0 + 1);
    uint4 wr0 = *(const uint4*)&wb[((b0 ^ e7) << 3)];
    uint4 wr1 = *(const uint4*)&wb[((b1 ^ e7) << 3)];

    // ---- MFMA + store NEXT tile (hides w-load latency; loads precede stores) ----
    if (nt + 4 < 54) { MFMA_STORE(nt + 4) }

    // ---- compute current tile ----
    if (m1 == 32) {
      if (nk == 1)      COMP32(1)
      else if (nk == 3) COMP32(3)
      else              COMP32(5)
    } else if (m1 == 16) {
      if (nk == 1)      COMP16(1)
      else if (nk == 3) COMP16(3)
      else              COMP16(5)
    } else {
      if (nk == 1)      COMP8(1)
      else if (nk == 3) COMP8(3)
      else              COMP8(5)
    }
  }

  __syncthreads();
  // coalesced msg1 write: block's 16 edges are 1920 contiguous floats
  const float s = 0.3162277660168379f;
  for (int i = tid; i < 1920; i += 256) {
    int e = i / 120, c = i - e*120;
    msg1[(size_t)e0*120 + i] = msgl[e*121 + c] * s;
  }
}

// ================= output: dst-CSR msg1 aggregation + self-connection =================
__global__ void k_out(const float* __restrict__ msg1,
                      const int* __restrict__ start2, const int* __restrict__ perm2,
                      const float* __restrict__ node1,
                      const float* __restrict__ sc0e, const float* __restrict__ sc1o,
                      const float* __restrict__ sc2e, float* __restrict__ out) {
  __shared__ float x[120];
  int n = blockIdx.x, tid = threadIdx.x;
  if (tid < 120) x[tid] = node1[(size_t)n*120 + tid];
  __syncthreads();
  if (tid >= 120) return;
  float v = 0.f;
  const int s0 = start2[n], s1 = start2[n+1];
  for (int idx = s0; idx < s1; ++idx)
    v += msg1[(size_t)perm2[idx]*120 + tid];
  if (tid < 32) {
    float s = 0.f;
    for (int u = 0; u < 32; ++u) s += x[u]*sc0e[u*32 + tid];
    v += s * 0.1767766952966369f;
  } else if (tid < 80) {
    int jj = tid - 32, vv = jj/3, k = jj - vv*3;
    float s = 0.f;
    for (int u = 0; u < 16; ++u) s += x[32 + u*3 + k]*sc1o[u*16 + vv];
    v += s * 0.25f;
  } else {
    int jj = tid - 80, vv = jj/5, k = jj - vv*5;
    float s = 0.f;
    for (int u = 0; u < 8; ++u) s += x[80 + u*5 + k]*sc2e[u*8 + vv];
    v += s * 0.3535533905932738f;
  }
  out[(size_t)n*120 + tid] = v;
}

// ---------------- launch ----------------
extern "C" void kernel_launch(void* const* d_in, const int* in_sizes, int n_in,
                              void* d_out, int out_size, void* d_ws, size_t ws_size,
                              hipStream_t stream) {
  const float* embed   = (const float*)d_in[1];
  const float* rad_w1  = (const float*)d_in[2];
  const float* rad_b1  = (const float*)d_in[3];
  const float* rad_w2  = (const float*)d_in[4];
  const float* rad_b2  = (const float*)d_in[5];
  const float* wnn0_w1 = (const float*)d_in[6];
  const float* wnn0_w2 = (const float*)d_in[7];
  const float* wnn1_w1 = (const float*)d_in[8];
  const float* wnn1_w2 = (const float*)d_in[9];
  const float* sc0_0e  = (const float*)d_in[10];
  const float* sc1_0e  = (const float*)d_in[11];
  const float* sc1_1o  = (const float*)d_in[12];
  const float* sc1_2e  = (const float*)d_in[13];
  const float* edge_vec = (const float*)d_in[14];
  const float* edge_len = (const float*)d_in[15];
  const int*  anum    = (const int*)d_in[16];
  const int*  ei      = (const int*)d_in[17];

  float* ws = (float*)d_ws;
  float* shbuf = ws;                        // 600000
  float* bc    = ws + 600000;               // 400000
  bf16*  q1b   = (bf16*)(ws + 1000000);     // 1.6M f-slots
  float* node0 = ws + 2600000;              // 320000
  bf16*  node0b= (bf16*)(ws + 2920000);     // 160000 f-slots
  bf16*  W0rtb = (bf16*)(ws + 3080000);     // 114688 f-slots
  bf16*  W2t   = (bf16*)(ws + 3194688);     // 110592 f-slots
  bf16*  Mbb   = (bf16*)(ws + 3305280);     // 4096 f-slots
  float* bias0 = ws + 3309376;              // 64
  float* bias1 = ws + 3309440;              // 64
  int*   hist   = (int*)(ws + 3309504);     // 5000 (memset covers hist..cursor2)
  int*   cursor = (int*)(ws + 3314504);     // 5000
  int*   hist2  = (int*)(ws + 3319504);     // 5000
  int*   cursor2= (int*)(ws + 3324504);     // 5000
  int*   start  = (int*)(ws + 3329504);     // 5008
  int*   start2 = (int*)(ws + 3334512);     // 5008
  int*   perm   = (int*)(ws + 3339520);     // 50000
  int*   perm2  = (int*)(ws + 3389520);     // 50000
  float* node1 = ws + 3439520;              // 600000
  float* msg1  = ws + 4039520;              // 6000000 (50000 x 120)
  // layer-0-only region:
  float* q0    = ws + 10039520;             // 3200000
  float* zbuf  = ws + 13239520;             // 2800000 (50000 x 56)
  bf16*  G0    = (bf16*)(ws + 16039520);    // 17.92M bf16

  hipMemsetAsync(hist, 0, 20000*sizeof(int), stream);   // hist, cursor, hist2, cursor2

  k_setup<<<3222, 256, 0, stream>>>(edge_vec, edge_len, shbuf, bc,
                                    rad_w2, rad_b2, wnn0_w1, wnn1_w1, Mbb, bias0, bias1,
                                    embed, anum, node0, node0b,
                                    wnn0_w2, W0rtb, wnn1_w2, W2t, ei, hist, hist2);
  k_mid<<<1565, 256, 0, stream>>>(bc, rad_w1, rad_b1, Mbb, bias0, bias1,
                                  q0, q1b, hist, start, hist2, start2);
  k_pre0<<<196 + 14*157, 256, 0, stream>>>(ei, start, cursor, perm,
                                           start2, cursor2, perm2,
                                           node0b, W0rtb, G0);
  k_msg0z<<<NN, 256, 0, stream>>>(q0, G0, start, perm, zbuf);
  k_agg0<<<NN, 128, 0, stream>>>(zbuf, shbuf, start2, perm2, node0, sc0_0e, node1);

  // fused layer-1: GEMM + tensor-product contraction, no wbuf intermediate
  k_fuse<<<3125, 256, 0, stream>>>(q1b, W2t, node1, shbuf, ei, msg1);

  k_out<<<NN, 128, 0, stream>>>(msg1, start2, perm2, node1, sc1_0e, sc1_1o, sc1_2e, (float*)d_out);
}